// Round 15
// baseline (538.398 us; speedup 1.0000x reference)
//
#include <hip/hip_runtime.h>
#include <cstddef>

// ---------------------------------------------------------------------------
// SimpleModuleNet. B=256, D=64, E=16, H=W=64, PROJ=512, FC=1024, NA=2.
//
// R2: 64->64 convs on matrix pipe (mfma_f32_16x16x32_f16, f16 hi/lo split).
// R3: fc1 on matrix pipe. R4: proj MFMA + in-lane pool + coalesced writes.
// R5/R7: conv1 win[] in regs + oc split across blockIdx.z.
// R9: projm emits pool3 as f16 hi/lo planes (fc1m A = pure data).
// R10: never cap VGPR below live state (spill disaster).
// R14 POST-MORTEM: (a) conv1 asm-pin FAILED (VGPR 40->56 only, +1.6M bank
//     conflicts, 78->85us) -> removed; proper fix is launch_bounds(256,4)
//     which RAISES the compiler's VGPR budget to 128 (live ~90 fits).
//     (b) fc1m split-K 64 FAILED (occupancy flat, +33MB writes) -> back to 32.
// R15: fc1m loads A-fragments DIRECTLY from global (L2-resident f16 planes),
//     no A-LDS staging: halves LDS-pipe pressure (computed bottleneck:
//     ~300 LDS-cyc/wave/step vs 240 MFMA-cyc). LDS 40KB -> 20KB.
// ---------------------------------------------------------------------------

typedef _Float16 half8 __attribute__((ext_vector_type(8)));
typedef _Float16 half4_t __attribute__((ext_vector_type(4)));
typedef float f32x4 __attribute__((ext_vector_type(4)));

#define LO_SCALE 2048.0f
#define LO_INV (1.0f / 2048.0f)

// ---------------- generic weight transpose  [o][i](KxK) -> [(i*K+k)][o]
__global__ void transw_k(const float* __restrict__ src, float* __restrict__ dst,
                         int O, int I, int K, int total) {
    int id = blockIdx.x * 256 + threadIdx.x;
    if (id >= total) return;
    int OIK = O * I * K;
    int n = id / OIK, rem = id % OIK;
    int o = rem / (I * K), r2 = rem % (I * K);
    int i = r2 / K, k = r2 % K;
    dst[(size_t)n * OIK + (i * K + k) * O + o] = src[id];
}

// ---------------- conv weight transform: [layer][oc=64][ic=64][3][3] fp32 ->
// f16 fragment layout: idx = (((tap*2+icc)*4+nt)*64 + lane)*8 + j
__global__ void wxform_k(const float* __restrict__ src, _Float16* __restrict__ dst,
                         int nlayers) {
    int id = blockIdx.x * 256 + threadIdx.x;
    if (id >= nlayers * 36864) return;
    int layer = id / 36864, idx = id % 36864;
    int j = idx & 7, l = (idx >> 3) & 63, nt = (idx >> 9) & 3;
    int icc = (idx >> 11) & 1, tap = idx >> 12;
    int kl = (l >> 4) * 8 + j, ic = icc * 32 + kl, oc = nt * 16 + (l & 15);
    float v = src[(size_t)layer * 36864 + (oc * 64 + ic) * 9 + tap];
    _Float16 hi = (_Float16)v;
    _Float16 lo = (_Float16)((v - (float)hi) * LO_SCALE);
    dst[(size_t)layer * 73728 + idx] = hi;
    dst[(size_t)layer * 73728 + 36864 + idx] = lo;
}

// ---------------- proj weight transform: [512 oc][64 ic] fp32 -> B-frag hi/lo
__global__ void pwxform_k(const float* __restrict__ src, _Float16* __restrict__ dst) {
    int id = blockIdx.x * 256 + threadIdx.x;
    if (id >= 32768) return;
    int j = id & 7, l = (id >> 3) & 63, icc = (id >> 9) & 1, nt = id >> 10;
    int kl = (l >> 4) * 8 + j, ic = icc * 32 + kl, oc = nt * 16 + (l & 15);
    float v = src[oc * 64 + ic];
    _Float16 hi = (_Float16)v;
    _Float16 lo = (_Float16)((v - (float)hi) * LO_SCALE);
    dst[id] = hi;
    dst[32768 + id] = lo;
}

// ---------------- conv1: 3->64, 64x64, pad1, +bias, relu, 2x2 maxpool.
// launch_bounds(256,4): VGPR budget 128 (live ~90) so win[3][4][4] stays
// register-resident (compiler's default heuristic chose 40 -> LDS rereads).
__global__ __launch_bounds__(256, 4)
void conv1_k(const float* __restrict__ img, const float* __restrict__ w0t,
             const float* __restrict__ b0, float* __restrict__ out) {
    int b = blockIdx.x, tile = blockIdx.y, ocg = blockIdx.z;
    int typ = (tile >> 1) * 16, txp = (tile & 1) * 16;
    int cy0 = typ * 2, cx0 = txp * 2;
    __shared__ float lds[3][34][34];
    const float* imb = img + (size_t)b * 3 * 64 * 64;
    for (int i = threadIdx.x; i < 3 * 34 * 34; i += 256) {
        int c = i / 1156, rem = i % 1156, r = rem / 34, cc = rem % 34;
        int gy = cy0 - 1 + r, gx = cx0 - 1 + cc;
        float v = 0.f;
        if (gy >= 0 && gy < 64 && gx >= 0 && gx < 64) v = imb[(c * 64 + gy) * 64 + gx];
        lds[c][r][cc] = v;
    }
    __syncthreads();
    int pyl = threadIdx.x >> 4, pxl = threadIdx.x & 15;
    float win[3][4][4];
#pragma unroll
    for (int c = 0; c < 3; ++c)
#pragma unroll
        for (int wy = 0; wy < 4; ++wy)
#pragma unroll
            for (int wx = 0; wx < 4; ++wx)
                win[c][wy][wx] = lds[c][2 * pyl + wy][2 * pxl + wx];
    int py = typ + pyl, px = txp + pxl;
    float* op = &out[(((size_t)b * 32 + py) * 32 + px) * 64];
#pragma unroll
    for (int q = 0; q < 4; ++q) {
        int ocq = ocg * 4 + q;
        float acc[4][4] = {};
#pragma unroll
        for (int c = 0; c < 3; ++c)
#pragma unroll
            for (int ky = 0; ky < 3; ++ky)
#pragma unroll
                for (int kx = 0; kx < 3; ++kx) {
                    float4 w = *(const float4*)&w0t[(c * 9 + ky * 3 + kx) * 64 + ocq * 4];
                    float wv4[4] = {w.x, w.y, w.z, w.w};
#pragma unroll
                    for (int p2 = 0; p2 < 4; ++p2) {
                        float iv = win[c][(p2 >> 1) + ky][(p2 & 1) + kx];
#pragma unroll
                        for (int o = 0; o < 4; ++o)
                            acc[p2][o] = fmaf(iv, wv4[o], acc[p2][o]);
                    }
                }
        float4 res;
        float* rp = (float*)&res;
#pragma unroll
        for (int o = 0; o < 4; ++o) {
            float bvv = b0[ocq * 4 + o];
            float m = fmaxf(fmaxf(acc[0][o], acc[1][o]), fmaxf(acc[2][o], acc[3][o]));
            rp[o] = fmaxf(m + bvv, 0.f);
        }
        *(float4*)&op[ocq * 4] = res;
    }
}

// ---------------- MFMA conv 64->64 3x3 pad1, NHWC fp32 in/out.
template <int S, bool POOL, bool RES>
__global__ __launch_bounds__(256, 2)
void convm_k(const float* __restrict__ in, float* __restrict__ out,
             const _Float16* __restrict__ wf, const float* __restrict__ bias,
             const float* __restrict__ res, const int* __restrict__ question,
             int qcol) {
    int b = blockIdx.x, t = blockIdx.y;
    constexpr int NTX = S / 16;
    int ty0 = (t / NTX) * 8, tx0 = (t % NTX) * 16;

    __shared__ __align__(16) _Float16 lds[2 * 7200];

    int tid = threadIdx.x, lane = tid & 63, wv = tid >> 6;
    const _Float16* wb = wf;
    const float* bb = bias;
    if (question) {
        int idx = question[b * 8 + qcol];
        wb += (size_t)idx * 73728;
        bb += idx * 64;
    }
    float bv[4];
#pragma unroll
    for (int nt = 0; nt < 4; ++nt) bv[nt] = bb[nt * 16 + (lane & 15)];

    f32x4 acc1[2][4] = {};
    f32x4 acc2[2][4] = {};

    int am = lane & 15;
    int k0 = (lane >> 4) * 8;

    for (int icc = 0; icc < 2; ++icc) {
        __syncthreads();
        for (int i = tid; i < 1440; i += 256) {
            int pix = i >> 3, j4 = i & 7;
            int hy = pix / 18, hx = pix % 18;
            int gy = ty0 + hy - 1, gx = tx0 + hx - 1;
            float4 v = {0.f, 0.f, 0.f, 0.f};
            if (gy >= 0 && gy < S && gx >= 0 && gx < S)
                v = *(const float4*)&in[(((size_t)b * S + gy) * S + gx) * 64 + icc * 32 + j4 * 4];
            _Float16 h0 = (_Float16)v.x, h1 = (_Float16)v.y;
            _Float16 h2 = (_Float16)v.z, h3 = (_Float16)v.w;
            half4_t hh = {h0, h1, h2, h3};
            half4_t ll = {(_Float16)((v.x - (float)h0) * LO_SCALE),
                          (_Float16)((v.y - (float)h1) * LO_SCALE),
                          (_Float16)((v.z - (float)h2) * LO_SCALE),
                          (_Float16)((v.w - (float)h3) * LO_SCALE)};
            *(half4_t*)&lds[pix * 40 + j4 * 4] = hh;
            *(half4_t*)&lds[7200 + pix * 40 + j4 * 4] = ll;
        }
        __syncthreads();

#pragma unroll
        for (int ky = 0; ky < 3; ++ky)
#pragma unroll
            for (int kx = 0; kx < 3; ++kx) {
                int tap = ky * 3 + kx;
                const _Float16* wp = wb + (tap * 2 + icc) * 2048 + lane * 8;
                half8 bhi[4], blo[4];
#pragma unroll
                for (int nt = 0; nt < 4; ++nt) {
                    bhi[nt] = *(const half8*)(wp + nt * 512);
                    blo[nt] = *(const half8*)(wp + nt * 512 + 36864);
                }
#pragma unroll
                for (int mt = 0; mt < 2; ++mt) {
                    int MT = wv * 2 + mt;
                    int Q = MT * 4 + (am >> 2), s = am & 3;
                    int py = (Q >> 3) * 2 + (s >> 1), px = (Q & 7) * 2 + (s & 1);
                    const _Float16* ap = &lds[((py + ky) * 18 + (px + kx)) * 40 + k0];
                    half8 ahi = *(const half8*)ap;
                    half8 alo = *(const half8*)(ap + 7200);
#pragma unroll
                    for (int nt = 0; nt < 4; ++nt) {
                        acc1[mt][nt] = __builtin_amdgcn_mfma_f32_16x16x32_f16(
                            ahi, bhi[nt], acc1[mt][nt], 0, 0, 0);
                        acc2[mt][nt] = __builtin_amdgcn_mfma_f32_16x16x32_f16(
                            ahi, blo[nt], acc2[mt][nt], 0, 0, 0);
                        acc2[mt][nt] = __builtin_amdgcn_mfma_f32_16x16x32_f16(
                            alo, bhi[nt], acc2[mt][nt], 0, 0, 0);
                    }
                }
            }
    }

    int cn = lane & 15, rq = lane >> 4;
#pragma unroll
    for (int mt = 0; mt < 2; ++mt) {
        int MT = wv * 2 + mt;
        int Q = MT * 4 + rq;
        int qy = Q >> 3, qx = Q & 7;
#pragma unroll
        for (int nt = 0; nt < 4; ++nt) {
            int oc = nt * 16 + cn;
            float vals[4];
#pragma unroll
            for (int r = 0; r < 4; ++r)
                vals[r] = acc1[mt][nt][r] + acc2[mt][nt][r] * LO_INV + bv[nt];
            if (POOL) {
                float m = fmaxf(fmaxf(vals[0], vals[1]), fmaxf(vals[2], vals[3]));
                m = fmaxf(m, 0.f);
                int opy = (ty0 >> 1) + qy, opx = (tx0 >> 1) + qx;
                out[(((size_t)b * (S / 2) + opy) * (S / 2) + opx) * 64 + oc] = m;
            } else {
#pragma unroll
                for (int r = 0; r < 4; ++r) {
                    int py = qy * 2 + (r >> 1), px = qx * 2 + (r & 1);
                    size_t o = (((size_t)b * S + (ty0 + py)) * S + (tx0 + px)) * 64 + oc;
                    float v = vals[r];
                    if (RES) v += res[o];
                    out[o] = fmaxf(v, 0.f);
                }
            }
        }
    }
}

// ---------------- proj (MFMA): per-sample GEMM C[256px][512oc], K=64, f16
// hi/lo; in-lane 2x2 pool. Output: f16 hi/lo planes (outh, outh+8388608).
__global__ __launch_bounds__(256)
void projm_k(const float* __restrict__ in /*NHWC B,16,16,64*/,
             const _Float16* __restrict__ pw, const float* __restrict__ bias,
             _Float16* __restrict__ outh /* hi plane; lo at +8388608 */) {
    int b = blockIdx.x;
    __shared__ float lt[64 * 65];
    int tid = threadIdx.x, lane = tid & 63, wv = tid >> 6;
    int row = lane & 15, cseg = lane >> 4;

    half8 ah[4][2], al[4][2];
#pragma unroll
    for (int mt = 0; mt < 4; ++mt) {
        int MT = wv * 4 + mt;
        int Q = MT * 4 + (row >> 2), s = row & 3;
        int y = (Q >> 3) * 2 + (s >> 1), x = (Q & 7) * 2 + (s & 1);
        const float* ip = in + ((size_t)b * 256 + y * 16 + x) * 64 + cseg * 8;
#pragma unroll
        for (int icc = 0; icc < 2; ++icc) {
            float4 v0 = *(const float4*)(ip + icc * 32);
            float4 v1 = *(const float4*)(ip + icc * 32 + 4);
            _Float16 h0 = (_Float16)v0.x, h1 = (_Float16)v0.y;
            _Float16 h2 = (_Float16)v0.z, h3 = (_Float16)v0.w;
            _Float16 h4 = (_Float16)v1.x, h5 = (_Float16)v1.y;
            _Float16 h6 = (_Float16)v1.z, h7 = (_Float16)v1.w;
            ah[mt][icc] = (half8){h0, h1, h2, h3, h4, h5, h6, h7};
            al[mt][icc] = (half8){(_Float16)((v0.x - (float)h0) * LO_SCALE),
                                  (_Float16)((v0.y - (float)h1) * LO_SCALE),
                                  (_Float16)((v0.z - (float)h2) * LO_SCALE),
                                  (_Float16)((v0.w - (float)h3) * LO_SCALE),
                                  (_Float16)((v1.x - (float)h4) * LO_SCALE),
                                  (_Float16)((v1.y - (float)h5) * LO_SCALE),
                                  (_Float16)((v1.z - (float)h6) * LO_SCALE),
                                  (_Float16)((v1.w - (float)h7) * LO_SCALE)};
        }
    }

    for (int ogl = 0; ogl < 4; ++ogl) {
        int og = blockIdx.y * 4 + ogl;
        half8 bh[4][2], bl[4][2];
#pragma unroll
        for (int ntl = 0; ntl < 4; ++ntl)
#pragma unroll
            for (int icc = 0; icc < 2; ++icc) {
                int nt = og * 4 + ntl;
                const _Float16* wp = pw + ((nt * 2 + icc) * 64 + lane) * 8;
                bh[ntl][icc] = *(const half8*)wp;
                bl[ntl][icc] = *(const half8*)(wp + 32768);
            }
        f32x4 a1[4][4] = {};
        f32x4 a2[4][4] = {};
#pragma unroll
        for (int icc = 0; icc < 2; ++icc)
#pragma unroll
            for (int mt = 0; mt < 4; ++mt)
#pragma unroll
                for (int ntl = 0; ntl < 4; ++ntl) {
                    a1[mt][ntl] = __builtin_amdgcn_mfma_f32_16x16x32_f16(
                        ah[mt][icc], bh[ntl][icc], a1[mt][ntl], 0, 0, 0);
                    a2[mt][ntl] = __builtin_amdgcn_mfma_f32_16x16x32_f16(
                        ah[mt][icc], bl[ntl][icc], a2[mt][ntl], 0, 0, 0);
                    a2[mt][ntl] = __builtin_amdgcn_mfma_f32_16x16x32_f16(
                        al[mt][icc], bh[ntl][icc], a2[mt][ntl], 0, 0, 0);
                }
        if (ogl) __syncthreads();
#pragma unroll
        for (int mt = 0; mt < 4; ++mt) {
            int Qg = (wv * 4 + mt) * 4 + (lane >> 4);
#pragma unroll
            for (int ntl = 0; ntl < 4; ++ntl) {
                float bvv = bias[og * 64 + ntl * 16 + (lane & 15)];
                float v0 = a1[mt][ntl][0] + a2[mt][ntl][0] * LO_INV + bvv;
                float v1 = a1[mt][ntl][1] + a2[mt][ntl][1] * LO_INV + bvv;
                float v2 = a1[mt][ntl][2] + a2[mt][ntl][2] * LO_INV + bvv;
                float v3 = a1[mt][ntl][3] + a2[mt][ntl][3] * LO_INV + bvv;
                float m = fmaxf(fmaxf(fmaxf(v0, v1), fmaxf(v2, v3)), 0.f);
                lt[(ntl * 16 + (lane & 15)) * 65 + Qg] = m;
            }
        }
        __syncthreads();
#pragma unroll
        for (int r = 0; r < 16; ++r) {
            int f = r * 256 + tid;
            int ol = f >> 6, q = f & 63;
            float v = lt[ol * 65 + q];
            _Float16 h = (_Float16)v;
            _Float16 l = (_Float16)((v - (float)h) * LO_SCALE);
            size_t o = (size_t)b * 32768 + og * 4096 + ol * 64 + q;
            outh[o] = h;
            outh[8388608 + o] = l;
        }
    }
}

// ---------------- fc1 MFMA GEMM: C[256][1024] = A[256][32768] @ W[1024][32768]^T
// R15: A-fragments loaded DIRECTLY from global f16 hi/lo planes (L2-resident,
// no A-LDS staging/barrier pressure). Only W staged+converted in LDS (20KB).
// Split-K 32, grid 512, plain launch_bounds.
__global__ __launch_bounds__(256)
void fc1m_k(const _Float16* __restrict__ Ahl /* hi; lo at +8388608 */,
            const float* __restrict__ W,
            float* __restrict__ partial /* [32][256][1024] */) {
    int bid = blockIdx.x;
    int lid = (bid & 7) * 64 + (bid >> 3);   // bijective, 512 = 8*64
    int mt = lid & 1, nt = (lid >> 1) & 7, ks = lid >> 4;  // ks 0..31
    int m0 = mt * 128, n0 = nt * 128;
    const _Float16* Ab = Ahl + (size_t)m0 * 32768 + ks * 1024;
    const float* Wb = W + (size_t)n0 * 32768 + ks * 1024;

    __shared__ __align__(16) _Float16 sb[10240];  // W hi [0,5120), lo [5120,..)

    int tid = threadIdx.x, lane = tid & 63, wv = tid >> 6;
    int wm = (wv & 1) * 64, wn = (wv >> 1) * 64;
    int koff = (lane >> 4) * 8;
    int fr = lane & 15;

    f32x4 acc1[4][4] = {};
    f32x4 acc2[4][4] = {};

    // W staging: 4 passes x (row, 4-wide fp32 seg), convert to hi/lo.
    int wrow[4], wc4[4];
#pragma unroll
    for (int p = 0; p < 4; ++p) {
        int idx = p * 256 + tid;
        wrow[p] = idx >> 3;
        wc4[p] = (idx & 7) << 2;
    }

    float4 rw[4];
#pragma unroll
    for (int p = 0; p < 4; ++p)
        rw[p] = *(const float4*)&Wb[(size_t)wrow[p] * 32768 + wc4[p]];

    for (int kt = 0; kt < 32; ++kt) {
#pragma unroll
        for (int p = 0; p < 4; ++p) {
            float4 u = rw[p];
            _Float16 g0 = (_Float16)u.x, g1 = (_Float16)u.y;
            _Float16 g2 = (_Float16)u.z, g3 = (_Float16)u.w;
            half4_t gh = {g0, g1, g2, g3};
            half4_t gl = {(_Float16)((u.x - (float)g0) * LO_SCALE),
                          (_Float16)((u.y - (float)g1) * LO_SCALE),
                          (_Float16)((u.z - (float)g2) * LO_SCALE),
                          (_Float16)((u.w - (float)g3) * LO_SCALE)};
            *(half4_t*)&sb[wrow[p] * 40 + wc4[p]] = gh;
            *(half4_t*)&sb[5120 + wrow[p] * 40 + wc4[p]] = gl;
        }
        __syncthreads();
        if (kt < 31) {
            int kb = (kt + 1) * 32;
#pragma unroll
            for (int p = 0; p < 4; ++p)
                rw[p] = *(const float4*)&Wb[(size_t)wrow[p] * 32768 + kb + wc4[p]];
        }
        // B fragments from LDS
        half8 bh[4], bl[4];
#pragma unroll
        for (int nf = 0; nf < 4; ++nf) {
            int r = wn + nf * 16 + fr;
            bh[nf] = *(const half8*)&sb[r * 40 + koff];
            bl[nf] = *(const half8*)&sb[5120 + r * 40 + koff];
        }
        // A fragments DIRECT from global (f16 hi/lo planes, L2-resident)
        int ka = kt * 32 + koff;
#pragma unroll
        for (int mf = 0; mf < 4; ++mf) {
            const _Float16* ap = Ab + (size_t)(wm + mf * 16 + fr) * 32768 + ka;
            half8 ah = *(const half8*)ap;
            half8 al = *(const half8*)(ap + 8388608);
#pragma unroll
            for (int nf = 0; nf < 4; ++nf) {
                acc1[mf][nf] = __builtin_amdgcn_mfma_f32_16x16x32_f16(
                    ah, bh[nf], acc1[mf][nf], 0, 0, 0);
                acc2[mf][nf] = __builtin_amdgcn_mfma_f32_16x16x32_f16(
                    ah, bl[nf], acc2[mf][nf], 0, 0, 0);
                acc2[mf][nf] = __builtin_amdgcn_mfma_f32_16x16x32_f16(
                    al, bh[nf], acc2[mf][nf], 0, 0, 0);
            }
        }
        __syncthreads();
    }

    int rq = lane >> 4, cn = lane & 15;
    float* pb = partial + (size_t)ks * 262144;
#pragma unroll
    for (int mf = 0; mf < 4; ++mf)
#pragma unroll
        for (int nf = 0; nf < 4; ++nf) {
            int n = n0 + wn + nf * 16 + cn;
#pragma unroll
            for (int r = 0; r < 4; ++r) {
                int m = m0 + wm + mf * 16 + rq * 4 + r;
                pb[(size_t)m * 1024 + n] = acc1[mf][nf][r] + acc2[mf][nf][r] * LO_INV;
            }
        }
}

__global__ __launch_bounds__(256)
void fc1red_k(const float* __restrict__ partial, const float* __restrict__ b1,
              float* __restrict__ fc1o_t /* [n][m] */) {
    int m = blockIdx.x;
    int n0 = threadIdx.x * 4;
    float4 s = {0.f, 0.f, 0.f, 0.f};
    for (int ks = 0; ks < 32; ++ks) {
        float4 v = *(const float4*)&partial[((size_t)ks * 256 + m) * 1024 + n0];
        s.x += v.x; s.y += v.y; s.z += v.z; s.w += v.w;
    }
    fc1o_t[(size_t)(n0 + 0) * 256 + m] = fmaxf(s.x + b1[n0 + 0], 0.f);
    fc1o_t[(size_t)(n0 + 1) * 256 + m] = fmaxf(s.y + b1[n0 + 1], 0.f);
    fc1o_t[(size_t)(n0 + 2) * 256 + m] = fmaxf(s.z + b1[n0 + 2], 0.f);
    fc1o_t[(size_t)(n0 + 3) * 256 + m] = fmaxf(s.w + b1[n0 + 3], 0.f);
}

__global__ __launch_bounds__(256)
void fc2a_k(const float* __restrict__ a_t, const float* __restrict__ W2,
            float* __restrict__ p2) {
    int n2 = blockIdx.x, ks = blockIdx.y;
    int m = threadIdx.x;
    float acc = 0.f;
    for (int k = ks * 256; k < ks * 256 + 256; ++k)
        acc = fmaf(a_t[(size_t)k * 256 + m], W2[n2 * 1024 + k], acc);
    p2[((size_t)n2 * 4 + ks) * 256 + m] = acc;
}

__global__ __launch_bounds__(512)
void fc2b_k(const float* __restrict__ p2, const float* __restrict__ b2,
            float* __restrict__ out) {
    int i = threadIdx.x;
    int m = i >> 1, n2 = i & 1;
    float s = b2[n2];
#pragma unroll
    for (int ks = 0; ks < 4; ++ks) s += p2[((size_t)n2 * 4 + ks) * 256 + m];
    out[m * 2 + n2] = s;
}

// ---------------------------------------------------------------------------
extern "C" void kernel_launch(void* const* d_in, const int* in_sizes, int n_in,
                              void* d_out, int out_size, void* d_ws, size_t ws_size,
                              hipStream_t stream) {
    const float* image   = (const float*)d_in[0];
    const int*   question= (const int*)d_in[1];
    const float* stem_w0 = (const float*)d_in[2];
    const float* stem_b0 = (const float*)d_in[3];
    const float* stem_w  = (const float*)d_in[4];
    const float* stem_b  = (const float*)d_in[5];
    const float* exp_w1  = (const float*)d_in[6];
    const float* exp_b1  = (const float*)d_in[7];
    const float* exp_w2  = (const float*)d_in[8];
    const float* exp_b2  = (const float*)d_in[9];
    const float* proj_w  = (const float*)d_in[10];
    const float* proj_b  = (const float*)d_in[11];
    const float* fc1_w   = (const float*)d_in[12];
    const float* fc1_b   = (const float*)d_in[13];
    const float* fc2_w   = (const float*)d_in[14];
    const float* fc2_b   = (const float*)d_in[15];
    (void)in_sizes; (void)n_in; (void)out_size; (void)ws_size;

    float* ws = (float*)d_ws;
    // Workspace (floats), peak ~156 MB:
    //  [0,A)        p1 NHWC; later hA/hB/hC (3*P2N); then fc1 partials
    //               [32][256][1024]
    //  [A,2A)       h2 NHWC; later pool3 f16 hi/lo planes (33.5MB) + fc1o
    //  [2A,2A+P2N)  p2 NHWC (B,16,16,64)
    //  [2A+P2N,..)  w0t | proj B-frag f16 | pfc2 | conv f16 weight planes
    const size_t A = 16777216, P2N = 4194304;
    float* p1    = ws;
    float* h2    = ws + A;
    float* p2    = ws + 2 * A;
    float* wtr   = ws + 2 * A + P2N;
    float* w0t   = wtr;                      // 1728 fp32
    _Float16* pwF = (_Float16*)(wtr + 1728); // 65536 f16
    float* pfc2  = wtr + 1728 + 32768;       // 2048 fp32
    _Float16* f16b = (_Float16*)(wtr + 36544);
    _Float16* stemtF = f16b;                 // 3 layers * 73728 f16
    _Float16* e1tF   = f16b + 3 * 73728;     // 16 layers
    _Float16* e2tF   = e1tF + 16 * 73728;    // 16 layers
    float* hA    = ws;
    float* hB    = ws + P2N;
    float* hC    = ws + 2 * P2N;
    _Float16* pool3h = (_Float16*)h2;        // hi plane 8388608 f16; lo at +8388608
    float* fc1o  = h2 + 8388608;
    float* fc1p  = ws;                       // [32][256][1024]

    // weight transforms
    transw_k<<<(1728 + 255) / 256, 256, 0, stream>>>(stem_w0, w0t, 64, 3, 9, 1728);
    pwxform_k<<<128, 256, 0, stream>>>(proj_w, pwF);
    wxform_k<<<(3 * 36864 + 255) / 256, 256, 0, stream>>>(stem_w, stemtF, 3);
    wxform_k<<<(16 * 36864 + 255) / 256, 256, 0, stream>>>(exp_w1, e1tF, 16);
    wxform_k<<<(16 * 36864 + 255) / 256, 256, 0, stream>>>(exp_w2, e2tF, 16);

    // stem
    conv1_k<<<dim3(256, 4, 4), 256, 0, stream>>>(image, w0t, stem_b0, p1);
    convm_k<32, false, false><<<dim3(256, 8), 256, 0, stream>>>(
        p1, h2, stemtF, stem_b, nullptr, nullptr, 0);
    convm_k<32, true, false><<<dim3(256, 8), 256, 0, stream>>>(
        h2, p2, stemtF + 73728, stem_b + 64, nullptr, nullptr, 0);
    convm_k<16, false, false><<<dim3(256, 2), 256, 0, stream>>>(
        p2, hA, stemtF + 2 * 73728, stem_b + 128, nullptr, nullptr, 0);

    // expert residual rounds (cols 4,5,7)
    const int cols[3] = {4, 5, 7};
    float* hin = hA;
    float* hmid = hB;
    float* hout = hC;
    for (int r = 0; r < 3; ++r) {
        convm_k<16, false, false><<<dim3(256, 2), 256, 0, stream>>>(
            hin, hmid, e1tF, exp_b1, nullptr, question, cols[r]);
        convm_k<16, false, true><<<dim3(256, 2), 256, 0, stream>>>(
            hmid, hout, e2tF, exp_b2, hin, question, cols[r]);
        float* tp = hin; hin = hout; hout = hmid; hmid = tp;
    }
    // hin == final h (ws+0)

    // head
    projm_k<<<dim3(256, 2), 256, 0, stream>>>(hin, pwF, proj_b, pool3h);
    fc1m_k<<<512, 256, 0, stream>>>(pool3h, fc1_w, fc1p);
    fc1red_k<<<256, 256, 0, stream>>>(fc1p, fc1_b, fc1o);
    fc2a_k<<<dim3(2, 4), 256, 0, stream>>>(fc1o, fc2_w, pfc2);
    fc2b_k<<<1, 512, 0, stream>>>(pfc2, fc2_b, (float*)d_out);
}

// Round 16
// 468.418 us; speedup vs baseline: 1.1494x; 1.1494x over previous
//
#include <hip/hip_runtime.h>
#include <cstddef>

// ---------------------------------------------------------------------------
// SimpleModuleNet. B=256, D=64, E=16, H=W=64, PROJ=512, FC=1024, NA=2.
//
// R2: 64->64 convs on matrix pipe (mfma_f32_16x16x32_f16, f16 hi/lo split).
// R4: proj MFMA + in-lane pool + coalesced writes. R9: pool3 as f16 planes.
// R5/R7: conv1 oc split across blockIdx.z. R15: conv1 launch_bounds(256,4)
//     raises VGPR budget -> win[] register-resident (worked; kept).
// R10: never cap VGPR below live state. R14: asm-pin and split-K-64 failed.
// R15 POST-MORTEM: direct-global-A fc1m FAILED (148us; per-step A loads
//     latency-exposed between barriers, no prefetch stage). Lesson: LDS +
//     reg-prefetch IS the pipeline.
// R16: fc1m = proven R11 structure (split-K 32, A planes reg->LDS, W
//     converted in-kernel, reg prefetch) + DOUBLE-BUFFERED LDS with ONE
//     barrier per K-step (write buf^1 -> issue next loads -> ds_read cur +
//     MFMA -> barrier). 80KB LDS, 2 blocks/CU.
// ---------------------------------------------------------------------------

typedef _Float16 half8 __attribute__((ext_vector_type(8)));
typedef _Float16 half4_t __attribute__((ext_vector_type(4)));
typedef float f32x4 __attribute__((ext_vector_type(4)));

#define LO_SCALE 2048.0f
#define LO_INV (1.0f / 2048.0f)

// ---------------- generic weight transpose  [o][i](KxK) -> [(i*K+k)][o]
__global__ void transw_k(const float* __restrict__ src, float* __restrict__ dst,
                         int O, int I, int K, int total) {
    int id = blockIdx.x * 256 + threadIdx.x;
    if (id >= total) return;
    int OIK = O * I * K;
    int n = id / OIK, rem = id % OIK;
    int o = rem / (I * K), r2 = rem % (I * K);
    int i = r2 / K, k = r2 % K;
    dst[(size_t)n * OIK + (i * K + k) * O + o] = src[id];
}

// ---------------- conv weight transform: [layer][oc=64][ic=64][3][3] fp32 ->
// f16 fragment layout: idx = (((tap*2+icc)*4+nt)*64 + lane)*8 + j
__global__ void wxform_k(const float* __restrict__ src, _Float16* __restrict__ dst,
                         int nlayers) {
    int id = blockIdx.x * 256 + threadIdx.x;
    if (id >= nlayers * 36864) return;
    int layer = id / 36864, idx = id % 36864;
    int j = idx & 7, l = (idx >> 3) & 63, nt = (idx >> 9) & 3;
    int icc = (idx >> 11) & 1, tap = idx >> 12;
    int kl = (l >> 4) * 8 + j, ic = icc * 32 + kl, oc = nt * 16 + (l & 15);
    float v = src[(size_t)layer * 36864 + (oc * 64 + ic) * 9 + tap];
    _Float16 hi = (_Float16)v;
    _Float16 lo = (_Float16)((v - (float)hi) * LO_SCALE);
    dst[(size_t)layer * 73728 + idx] = hi;
    dst[(size_t)layer * 73728 + 36864 + idx] = lo;
}

// ---------------- proj weight transform: [512 oc][64 ic] fp32 -> B-frag hi/lo
__global__ void pwxform_k(const float* __restrict__ src, _Float16* __restrict__ dst) {
    int id = blockIdx.x * 256 + threadIdx.x;
    if (id >= 32768) return;
    int j = id & 7, l = (id >> 3) & 63, icc = (id >> 9) & 1, nt = id >> 10;
    int kl = (l >> 4) * 8 + j, ic = icc * 32 + kl, oc = nt * 16 + (l & 15);
    float v = src[oc * 64 + ic];
    _Float16 hi = (_Float16)v;
    _Float16 lo = (_Float16)((v - (float)hi) * LO_SCALE);
    dst[id] = hi;
    dst[32768 + id] = lo;
}

// ---------------- conv1: 3->64, 64x64, pad1, +bias, relu, 2x2 maxpool.
// launch_bounds(256,4): VGPR budget 128 (live ~90) so win[3][4][4] stays
// register-resident (default heuristic chose 40 -> LDS rereads). [R15: kept]
__global__ __launch_bounds__(256, 4)
void conv1_k(const float* __restrict__ img, const float* __restrict__ w0t,
             const float* __restrict__ b0, float* __restrict__ out) {
    int b = blockIdx.x, tile = blockIdx.y, ocg = blockIdx.z;
    int typ = (tile >> 1) * 16, txp = (tile & 1) * 16;
    int cy0 = typ * 2, cx0 = txp * 2;
    __shared__ float lds[3][34][34];
    const float* imb = img + (size_t)b * 3 * 64 * 64;
    for (int i = threadIdx.x; i < 3 * 34 * 34; i += 256) {
        int c = i / 1156, rem = i % 1156, r = rem / 34, cc = rem % 34;
        int gy = cy0 - 1 + r, gx = cx0 - 1 + cc;
        float v = 0.f;
        if (gy >= 0 && gy < 64 && gx >= 0 && gx < 64) v = imb[(c * 64 + gy) * 64 + gx];
        lds[c][r][cc] = v;
    }
    __syncthreads();
    int pyl = threadIdx.x >> 4, pxl = threadIdx.x & 15;
    float win[3][4][4];
#pragma unroll
    for (int c = 0; c < 3; ++c)
#pragma unroll
        for (int wy = 0; wy < 4; ++wy)
#pragma unroll
            for (int wx = 0; wx < 4; ++wx)
                win[c][wy][wx] = lds[c][2 * pyl + wy][2 * pxl + wx];
    int py = typ + pyl, px = txp + pxl;
    float* op = &out[(((size_t)b * 32 + py) * 32 + px) * 64];
#pragma unroll
    for (int q = 0; q < 4; ++q) {
        int ocq = ocg * 4 + q;
        float acc[4][4] = {};
#pragma unroll
        for (int c = 0; c < 3; ++c)
#pragma unroll
            for (int ky = 0; ky < 3; ++ky)
#pragma unroll
                for (int kx = 0; kx < 3; ++kx) {
                    float4 w = *(const float4*)&w0t[(c * 9 + ky * 3 + kx) * 64 + ocq * 4];
                    float wv4[4] = {w.x, w.y, w.z, w.w};
#pragma unroll
                    for (int p2 = 0; p2 < 4; ++p2) {
                        float iv = win[c][(p2 >> 1) + ky][(p2 & 1) + kx];
#pragma unroll
                        for (int o = 0; o < 4; ++o)
                            acc[p2][o] = fmaf(iv, wv4[o], acc[p2][o]);
                    }
                }
        float4 res;
        float* rp = (float*)&res;
#pragma unroll
        for (int o = 0; o < 4; ++o) {
            float bvv = b0[ocq * 4 + o];
            float m = fmaxf(fmaxf(acc[0][o], acc[1][o]), fmaxf(acc[2][o], acc[3][o]));
            rp[o] = fmaxf(m + bvv, 0.f);
        }
        *(float4*)&op[ocq * 4] = res;
    }
}

// ---------------- MFMA conv 64->64 3x3 pad1, NHWC fp32 in/out.
template <int S, bool POOL, bool RES>
__global__ __launch_bounds__(256, 2)
void convm_k(const float* __restrict__ in, float* __restrict__ out,
             const _Float16* __restrict__ wf, const float* __restrict__ bias,
             const float* __restrict__ res, const int* __restrict__ question,
             int qcol) {
    int b = blockIdx.x, t = blockIdx.y;
    constexpr int NTX = S / 16;
    int ty0 = (t / NTX) * 8, tx0 = (t % NTX) * 16;

    __shared__ __align__(16) _Float16 lds[2 * 7200];

    int tid = threadIdx.x, lane = tid & 63, wv = tid >> 6;
    const _Float16* wb = wf;
    const float* bb = bias;
    if (question) {
        int idx = question[b * 8 + qcol];
        wb += (size_t)idx * 73728;
        bb += idx * 64;
    }
    float bv[4];
#pragma unroll
    for (int nt = 0; nt < 4; ++nt) bv[nt] = bb[nt * 16 + (lane & 15)];

    f32x4 acc1[2][4] = {};
    f32x4 acc2[2][4] = {};

    int am = lane & 15;
    int k0 = (lane >> 4) * 8;

    for (int icc = 0; icc < 2; ++icc) {
        __syncthreads();
        for (int i = tid; i < 1440; i += 256) {
            int pix = i >> 3, j4 = i & 7;
            int hy = pix / 18, hx = pix % 18;
            int gy = ty0 + hy - 1, gx = tx0 + hx - 1;
            float4 v = {0.f, 0.f, 0.f, 0.f};
            if (gy >= 0 && gy < S && gx >= 0 && gx < S)
                v = *(const float4*)&in[(((size_t)b * S + gy) * S + gx) * 64 + icc * 32 + j4 * 4];
            _Float16 h0 = (_Float16)v.x, h1 = (_Float16)v.y;
            _Float16 h2 = (_Float16)v.z, h3 = (_Float16)v.w;
            half4_t hh = {h0, h1, h2, h3};
            half4_t ll = {(_Float16)((v.x - (float)h0) * LO_SCALE),
                          (_Float16)((v.y - (float)h1) * LO_SCALE),
                          (_Float16)((v.z - (float)h2) * LO_SCALE),
                          (_Float16)((v.w - (float)h3) * LO_SCALE)};
            *(half4_t*)&lds[pix * 40 + j4 * 4] = hh;
            *(half4_t*)&lds[7200 + pix * 40 + j4 * 4] = ll;
        }
        __syncthreads();

#pragma unroll
        for (int ky = 0; ky < 3; ++ky)
#pragma unroll
            for (int kx = 0; kx < 3; ++kx) {
                int tap = ky * 3 + kx;
                const _Float16* wp = wb + (tap * 2 + icc) * 2048 + lane * 8;
                half8 bhi[4], blo[4];
#pragma unroll
                for (int nt = 0; nt < 4; ++nt) {
                    bhi[nt] = *(const half8*)(wp + nt * 512);
                    blo[nt] = *(const half8*)(wp + nt * 512 + 36864);
                }
#pragma unroll
                for (int mt = 0; mt < 2; ++mt) {
                    int MT = wv * 2 + mt;
                    int Q = MT * 4 + (am >> 2), s = am & 3;
                    int py = (Q >> 3) * 2 + (s >> 1), px = (Q & 7) * 2 + (s & 1);
                    const _Float16* ap = &lds[((py + ky) * 18 + (px + kx)) * 40 + k0];
                    half8 ahi = *(const half8*)ap;
                    half8 alo = *(const half8*)(ap + 7200);
#pragma unroll
                    for (int nt = 0; nt < 4; ++nt) {
                        acc1[mt][nt] = __builtin_amdgcn_mfma_f32_16x16x32_f16(
                            ahi, bhi[nt], acc1[mt][nt], 0, 0, 0);
                        acc2[mt][nt] = __builtin_amdgcn_mfma_f32_16x16x32_f16(
                            ahi, blo[nt], acc2[mt][nt], 0, 0, 0);
                        acc2[mt][nt] = __builtin_amdgcn_mfma_f32_16x16x32_f16(
                            alo, bhi[nt], acc2[mt][nt], 0, 0, 0);
                    }
                }
            }
    }

    int cn = lane & 15, rq = lane >> 4;
#pragma unroll
    for (int mt = 0; mt < 2; ++mt) {
        int MT = wv * 2 + mt;
        int Q = MT * 4 + rq;
        int qy = Q >> 3, qx = Q & 7;
#pragma unroll
        for (int nt = 0; nt < 4; ++nt) {
            int oc = nt * 16 + cn;
            float vals[4];
#pragma unroll
            for (int r = 0; r < 4; ++r)
                vals[r] = acc1[mt][nt][r] + acc2[mt][nt][r] * LO_INV + bv[nt];
            if (POOL) {
                float m = fmaxf(fmaxf(vals[0], vals[1]), fmaxf(vals[2], vals[3]));
                m = fmaxf(m, 0.f);
                int opy = (ty0 >> 1) + qy, opx = (tx0 >> 1) + qx;
                out[(((size_t)b * (S / 2) + opy) * (S / 2) + opx) * 64 + oc] = m;
            } else {
#pragma unroll
                for (int r = 0; r < 4; ++r) {
                    int py = qy * 2 + (r >> 1), px = qx * 2 + (r & 1);
                    size_t o = (((size_t)b * S + (ty0 + py)) * S + (tx0 + px)) * 64 + oc;
                    float v = vals[r];
                    if (RES) v += res[o];
                    out[o] = fmaxf(v, 0.f);
                }
            }
        }
    }
}

// ---------------- proj (MFMA): per-sample GEMM C[256px][512oc], K=64, f16
// hi/lo; in-lane 2x2 pool. Output: f16 hi/lo planes (outh, outh+8388608).
__global__ __launch_bounds__(256)
void projm_k(const float* __restrict__ in /*NHWC B,16,16,64*/,
             const _Float16* __restrict__ pw, const float* __restrict__ bias,
             _Float16* __restrict__ outh /* hi plane; lo at +8388608 */) {
    int b = blockIdx.x;
    __shared__ float lt[64 * 65];
    int tid = threadIdx.x, lane = tid & 63, wv = tid >> 6;
    int row = lane & 15, cseg = lane >> 4;

    half8 ah[4][2], al[4][2];
#pragma unroll
    for (int mt = 0; mt < 4; ++mt) {
        int MT = wv * 4 + mt;
        int Q = MT * 4 + (row >> 2), s = row & 3;
        int y = (Q >> 3) * 2 + (s >> 1), x = (Q & 7) * 2 + (s & 1);
        const float* ip = in + ((size_t)b * 256 + y * 16 + x) * 64 + cseg * 8;
#pragma unroll
        for (int icc = 0; icc < 2; ++icc) {
            float4 v0 = *(const float4*)(ip + icc * 32);
            float4 v1 = *(const float4*)(ip + icc * 32 + 4);
            _Float16 h0 = (_Float16)v0.x, h1 = (_Float16)v0.y;
            _Float16 h2 = (_Float16)v0.z, h3 = (_Float16)v0.w;
            _Float16 h4 = (_Float16)v1.x, h5 = (_Float16)v1.y;
            _Float16 h6 = (_Float16)v1.z, h7 = (_Float16)v1.w;
            ah[mt][icc] = (half8){h0, h1, h2, h3, h4, h5, h6, h7};
            al[mt][icc] = (half8){(_Float16)((v0.x - (float)h0) * LO_SCALE),
                                  (_Float16)((v0.y - (float)h1) * LO_SCALE),
                                  (_Float16)((v0.z - (float)h2) * LO_SCALE),
                                  (_Float16)((v0.w - (float)h3) * LO_SCALE),
                                  (_Float16)((v1.x - (float)h4) * LO_SCALE),
                                  (_Float16)((v1.y - (float)h5) * LO_SCALE),
                                  (_Float16)((v1.z - (float)h6) * LO_SCALE),
                                  (_Float16)((v1.w - (float)h7) * LO_SCALE)};
        }
    }

    for (int ogl = 0; ogl < 4; ++ogl) {
        int og = blockIdx.y * 4 + ogl;
        half8 bh[4][2], bl[4][2];
#pragma unroll
        for (int ntl = 0; ntl < 4; ++ntl)
#pragma unroll
            for (int icc = 0; icc < 2; ++icc) {
                int nt = og * 4 + ntl;
                const _Float16* wp = pw + ((nt * 2 + icc) * 64 + lane) * 8;
                bh[ntl][icc] = *(const half8*)wp;
                bl[ntl][icc] = *(const half8*)(wp + 32768);
            }
        f32x4 a1[4][4] = {};
        f32x4 a2[4][4] = {};
#pragma unroll
        for (int icc = 0; icc < 2; ++icc)
#pragma unroll
            for (int mt = 0; mt < 4; ++mt)
#pragma unroll
                for (int ntl = 0; ntl < 4; ++ntl) {
                    a1[mt][ntl] = __builtin_amdgcn_mfma_f32_16x16x32_f16(
                        ah[mt][icc], bh[ntl][icc], a1[mt][ntl], 0, 0, 0);
                    a2[mt][ntl] = __builtin_amdgcn_mfma_f32_16x16x32_f16(
                        ah[mt][icc], bl[ntl][icc], a2[mt][ntl], 0, 0, 0);
                    a2[mt][ntl] = __builtin_amdgcn_mfma_f32_16x16x32_f16(
                        al[mt][icc], bh[ntl][icc], a2[mt][ntl], 0, 0, 0);
                }
        if (ogl) __syncthreads();
#pragma unroll
        for (int mt = 0; mt < 4; ++mt) {
            int Qg = (wv * 4 + mt) * 4 + (lane >> 4);
#pragma unroll
            for (int ntl = 0; ntl < 4; ++ntl) {
                float bvv = bias[og * 64 + ntl * 16 + (lane & 15)];
                float v0 = a1[mt][ntl][0] + a2[mt][ntl][0] * LO_INV + bvv;
                float v1 = a1[mt][ntl][1] + a2[mt][ntl][1] * LO_INV + bvv;
                float v2 = a1[mt][ntl][2] + a2[mt][ntl][2] * LO_INV + bvv;
                float v3 = a1[mt][ntl][3] + a2[mt][ntl][3] * LO_INV + bvv;
                float m = fmaxf(fmaxf(fmaxf(v0, v1), fmaxf(v2, v3)), 0.f);
                lt[(ntl * 16 + (lane & 15)) * 65 + Qg] = m;
            }
        }
        __syncthreads();
#pragma unroll
        for (int r = 0; r < 16; ++r) {
            int f = r * 256 + tid;
            int ol = f >> 6, q = f & 63;
            float v = lt[ol * 65 + q];
            _Float16 h = (_Float16)v;
            _Float16 l = (_Float16)((v - (float)h) * LO_SCALE);
            size_t o = (size_t)b * 32768 + og * 4096 + ol * 64 + q;
            outh[o] = h;
            outh[8388608 + o] = l;
        }
    }
}

// ---------------- fc1 MFMA GEMM: C[256][1024] = A[256][32768] @ W[1024][32768]^T
// R16: double-buffered LDS, ONE barrier per K-step. Per buffer (20480 f16):
// A hi [0,5120) lo [5120,10240); W hi [10240,15360) lo [15360,20480).
// A pre-split f16 planes -> pure-copy staging; W converted in-kernel.
// Split-K 32, grid 512, plain launch_bounds (no VGPR cap).
__global__ __launch_bounds__(256)
void fc1m_k(const _Float16* __restrict__ Ahl /* hi; lo at +8388608 */,
            const float* __restrict__ W,
            float* __restrict__ partial /* [32][256][1024] */) {
    int bid = blockIdx.x;
    int lid = (bid & 7) * 64 + (bid >> 3);   // bijective, 512 = 8*64
    int mt = lid & 1, nt = (lid >> 1) & 7, ks = lid >> 4;  // ks 0..31
    int m0 = mt * 128, n0 = nt * 128;
    const _Float16* Ab = Ahl + (size_t)m0 * 32768 + ks * 1024;
    const float* Wb = W + (size_t)n0 * 32768 + ks * 1024;

    __shared__ __align__(16) _Float16 lds[40960];  // 2 buffers x 20480

    int tid = threadIdx.x, lane = tid & 63, wv = tid >> 6;
    int wm = (wv & 1) * 64, wn = (wv >> 1) * 64;
    int koff = (lane >> 4) * 8, fr = lane & 15;

    f32x4 acc1[4][4] = {};
    f32x4 acc2[4][4] = {};

    int arow[2], ak8[2];
#pragma unroll
    for (int p = 0; p < 2; ++p) {
        int idx = p * 256 + tid;
        arow[p] = idx >> 2;
        ak8[p] = (idx & 3) * 8;
    }
    int wrow[4], wc4[4];
#pragma unroll
    for (int p = 0; p < 4; ++p) {
        int idx = p * 256 + tid;
        wrow[p] = idx >> 3;
        wc4[p] = (idx & 7) << 2;
    }

    half8 pa_h[2], pa_l[2];
    float4 rw[4];

    // ---- prologue: tile 0 -> regs -> buf0; tile 1 -> regs; barrier
#pragma unroll
    for (int p = 0; p < 2; ++p) {
        pa_h[p] = *(const half8*)&Ab[(size_t)arow[p] * 32768 + ak8[p]];
        pa_l[p] = *(const half8*)&Ab[8388608 + (size_t)arow[p] * 32768 + ak8[p]];
    }
#pragma unroll
    for (int p = 0; p < 4; ++p)
        rw[p] = *(const float4*)&Wb[(size_t)wrow[p] * 32768 + wc4[p]];
    {
        _Float16* b0p = lds;
#pragma unroll
        for (int p = 0; p < 2; ++p) {
            *(half8*)&b0p[arow[p] * 40 + ak8[p]] = pa_h[p];
            *(half8*)&b0p[5120 + arow[p] * 40 + ak8[p]] = pa_l[p];
        }
#pragma unroll
        for (int p = 0; p < 4; ++p) {
            float4 u = rw[p];
            _Float16 g0 = (_Float16)u.x, g1 = (_Float16)u.y;
            _Float16 g2 = (_Float16)u.z, g3 = (_Float16)u.w;
            half4_t gh = {g0, g1, g2, g3};
            half4_t gl = {(_Float16)((u.x - (float)g0) * LO_SCALE),
                          (_Float16)((u.y - (float)g1) * LO_SCALE),
                          (_Float16)((u.z - (float)g2) * LO_SCALE),
                          (_Float16)((u.w - (float)g3) * LO_SCALE)};
            *(half4_t*)&b0p[10240 + wrow[p] * 40 + wc4[p]] = gh;
            *(half4_t*)&b0p[15360 + wrow[p] * 40 + wc4[p]] = gl;
        }
    }
    // issue tile-1 loads (consumed next iteration's staging write)
#pragma unroll
    for (int p = 0; p < 2; ++p) {
        pa_h[p] = *(const half8*)&Ab[(size_t)arow[p] * 32768 + 32 + ak8[p]];
        pa_l[p] = *(const half8*)&Ab[8388608 + (size_t)arow[p] * 32768 + 32 + ak8[p]];
    }
#pragma unroll
    for (int p = 0; p < 4; ++p)
        rw[p] = *(const float4*)&Wb[(size_t)wrow[p] * 32768 + 32 + wc4[p]];
    __syncthreads();

    for (int kt = 0; kt < 32; ++kt) {
        _Float16* cur = lds + (kt & 1) * 20480;
        _Float16* nxt = lds + ((kt + 1) & 1) * 20480;
        if (kt < 31) {
            // stage tile kt+1 (in regs) into nxt — nxt was fully read at kt-1
#pragma unroll
            for (int p = 0; p < 2; ++p) {
                *(half8*)&nxt[arow[p] * 40 + ak8[p]] = pa_h[p];
                *(half8*)&nxt[5120 + arow[p] * 40 + ak8[p]] = pa_l[p];
            }
#pragma unroll
            for (int p = 0; p < 4; ++p) {
                float4 u = rw[p];
                _Float16 g0 = (_Float16)u.x, g1 = (_Float16)u.y;
                _Float16 g2 = (_Float16)u.z, g3 = (_Float16)u.w;
                half4_t gh = {g0, g1, g2, g3};
                half4_t gl = {(_Float16)((u.x - (float)g0) * LO_SCALE),
                              (_Float16)((u.y - (float)g1) * LO_SCALE),
                              (_Float16)((u.z - (float)g2) * LO_SCALE),
                              (_Float16)((u.w - (float)g3) * LO_SCALE)};
                *(half4_t*)&nxt[10240 + wrow[p] * 40 + wc4[p]] = gh;
                *(half4_t*)&nxt[15360 + wrow[p] * 40 + wc4[p]] = gl;
            }
            if (kt < 30) {  // issue tile kt+2 loads; latency hides under MFMAs
                int kb = (kt + 2) * 32;
#pragma unroll
                for (int p = 0; p < 2; ++p) {
                    pa_h[p] = *(const half8*)&Ab[(size_t)arow[p] * 32768 + kb + ak8[p]];
                    pa_l[p] = *(const half8*)&Ab[8388608 + (size_t)arow[p] * 32768 + kb + ak8[p]];
                }
#pragma unroll
                for (int p = 0; p < 4; ++p)
                    rw[p] = *(const float4*)&Wb[(size_t)wrow[p] * 32768 + kb + wc4[p]];
            }
        }
        // fragments from cur + MFMAs
        half8 bh[4], bl[4];
#pragma unroll
        for (int nf = 0; nf < 4; ++nf) {
            int r = wn + nf * 16 + fr;
            bh[nf] = *(const half8*)&cur[10240 + r * 40 + koff];
            bl[nf] = *(const half8*)&cur[15360 + r * 40 + koff];
        }
#pragma unroll
        for (int mf = 0; mf < 4; ++mf) {
            int r = wm + mf * 16 + fr;
            half8 ah = *(const half8*)&cur[r * 40 + koff];
            half8 al = *(const half8*)&cur[5120 + r * 40 + koff];
#pragma unroll
            for (int nf = 0; nf < 4; ++nf) {
                acc1[mf][nf] = __builtin_amdgcn_mfma_f32_16x16x32_f16(
                    ah, bh[nf], acc1[mf][nf], 0, 0, 0);
                acc2[mf][nf] = __builtin_amdgcn_mfma_f32_16x16x32_f16(
                    ah, bl[nf], acc2[mf][nf], 0, 0, 0);
                acc2[mf][nf] = __builtin_amdgcn_mfma_f32_16x16x32_f16(
                    al, bh[nf], acc2[mf][nf], 0, 0, 0);
            }
        }
        __syncthreads();  // single barrier per K-step
    }

    int rq = lane >> 4, cn = lane & 15;
    float* pb = partial + (size_t)ks * 262144;
#pragma unroll
    for (int mf = 0; mf < 4; ++mf)
#pragma unroll
        for (int nf = 0; nf < 4; ++nf) {
            int n = n0 + wn + nf * 16 + cn;
#pragma unroll
            for (int r = 0; r < 4; ++r) {
                int m = m0 + wm + mf * 16 + rq * 4 + r;
                pb[(size_t)m * 1024 + n] = acc1[mf][nf][r] + acc2[mf][nf][r] * LO_INV;
            }
        }
}

__global__ __launch_bounds__(256)
void fc1red_k(const float* __restrict__ partial, const float* __restrict__ b1,
              float* __restrict__ fc1o_t /* [n][m] */) {
    int m = blockIdx.x;
    int n0 = threadIdx.x * 4;
    float4 s = {0.f, 0.f, 0.f, 0.f};
    for (int ks = 0; ks < 32; ++ks) {
        float4 v = *(const float4*)&partial[((size_t)ks * 256 + m) * 1024 + n0];
        s.x += v.x; s.y += v.y; s.z += v.z; s.w += v.w;
    }
    fc1o_t[(size_t)(n0 + 0) * 256 + m] = fmaxf(s.x + b1[n0 + 0], 0.f);
    fc1o_t[(size_t)(n0 + 1) * 256 + m] = fmaxf(s.y + b1[n0 + 1], 0.f);
    fc1o_t[(size_t)(n0 + 2) * 256 + m] = fmaxf(s.z + b1[n0 + 2], 0.f);
    fc1o_t[(size_t)(n0 + 3) * 256 + m] = fmaxf(s.w + b1[n0 + 3], 0.f);
}

__global__ __launch_bounds__(256)
void fc2a_k(const float* __restrict__ a_t, const float* __restrict__ W2,
            float* __restrict__ p2) {
    int n2 = blockIdx.x, ks = blockIdx.y;
    int m = threadIdx.x;
    float acc = 0.f;
    for (int k = ks * 256; k < ks * 256 + 256; ++k)
        acc = fmaf(a_t[(size_t)k * 256 + m], W2[n2 * 1024 + k], acc);
    p2[((size_t)n2 * 4 + ks) * 256 + m] = acc;
}

__global__ __launch_bounds__(512)
void fc2b_k(const float* __restrict__ p2, const float* __restrict__ b2,
            float* __restrict__ out) {
    int i = threadIdx.x;
    int m = i >> 1, n2 = i & 1;
    float s = b2[n2];
#pragma unroll
    for (int ks = 0; ks < 4; ++ks) s += p2[((size_t)n2 * 4 + ks) * 256 + m];
    out[m * 2 + n2] = s;
}

// ---------------------------------------------------------------------------
extern "C" void kernel_launch(void* const* d_in, const int* in_sizes, int n_in,
                              void* d_out, int out_size, void* d_ws, size_t ws_size,
                              hipStream_t stream) {
    const float* image   = (const float*)d_in[0];
    const int*   question= (const int*)d_in[1];
    const float* stem_w0 = (const float*)d_in[2];
    const float* stem_b0 = (const float*)d_in[3];
    const float* stem_w  = (const float*)d_in[4];
    const float* stem_b  = (const float*)d_in[5];
    const float* exp_w1  = (const float*)d_in[6];
    const float* exp_b1  = (const float*)d_in[7];
    const float* exp_w2  = (const float*)d_in[8];
    const float* exp_b2  = (const float*)d_in[9];
    const float* proj_w  = (const float*)d_in[10];
    const float* proj_b  = (const float*)d_in[11];
    const float* fc1_w   = (const float*)d_in[12];
    const float* fc1_b   = (const float*)d_in[13];
    const float* fc2_w   = (const float*)d_in[14];
    const float* fc2_b   = (const float*)d_in[15];
    (void)in_sizes; (void)n_in; (void)out_size; (void)ws_size;

    float* ws = (float*)d_ws;
    // Workspace (floats), peak ~156 MB:
    //  [0,A)        p1 NHWC; later hA/hB/hC (3*P2N); then fc1 partials
    //               [32][256][1024]
    //  [A,2A)       h2 NHWC; later pool3 f16 hi/lo planes (33.5MB) + fc1o
    //  [2A,2A+P2N)  p2 NHWC (B,16,16,64)
    //  [2A+P2N,..)  w0t | proj B-frag f16 | pfc2 | conv f16 weight planes
    const size_t A = 16777216, P2N = 4194304;
    float* p1    = ws;
    float* h2    = ws + A;
    float* p2    = ws + 2 * A;
    float* wtr   = ws + 2 * A + P2N;
    float* w0t   = wtr;                      // 1728 fp32
    _Float16* pwF = (_Float16*)(wtr + 1728); // 65536 f16
    float* pfc2  = wtr + 1728 + 32768;       // 2048 fp32
    _Float16* f16b = (_Float16*)(wtr + 36544);
    _Float16* stemtF = f16b;                 // 3 layers * 73728 f16
    _Float16* e1tF   = f16b + 3 * 73728;     // 16 layers
    _Float16* e2tF   = e1tF + 16 * 73728;    // 16 layers
    float* hA    = ws;
    float* hB    = ws + P2N;
    float* hC    = ws + 2 * P2N;
    _Float16* pool3h = (_Float16*)h2;        // hi plane 8388608 f16; lo at +8388608
    float* fc1o  = h2 + 8388608;
    float* fc1p  = ws;                       // [32][256][1024]

    // weight transforms
    transw_k<<<(1728 + 255) / 256, 256, 0, stream>>>(stem_w0, w0t, 64, 3, 9, 1728);
    pwxform_k<<<128, 256, 0, stream>>>(proj_w, pwF);
    wxform_k<<<(3 * 36864 + 255) / 256, 256, 0, stream>>>(stem_w, stemtF, 3);
    wxform_k<<<(16 * 36864 + 255) / 256, 256, 0, stream>>>(exp_w1, e1tF, 16);
    wxform_k<<<(16 * 36864 + 255) / 256, 256, 0, stream>>>(exp_w2, e2tF, 16);

    // stem
    conv1_k<<<dim3(256, 4, 4), 256, 0, stream>>>(image, w0t, stem_b0, p1);
    convm_k<32, false, false><<<dim3(256, 8), 256, 0, stream>>>(
        p1, h2, stemtF, stem_b, nullptr, nullptr, 0);
    convm_k<32, true, false><<<dim3(256, 8), 256, 0, stream>>>(
        h2, p2, stemtF + 73728, stem_b + 64, nullptr, nullptr, 0);
    convm_k<16, false, false><<<dim3(256, 2), 256, 0, stream>>>(
        p2, hA, stemtF + 2 * 73728, stem_b + 128, nullptr, nullptr, 0);

    // expert residual rounds (cols 4,5,7)
    const int cols[3] = {4, 5, 7};
    float* hin = hA;
    float* hmid = hB;
    float* hout = hC;
    for (int r = 0; r < 3; ++r) {
        convm_k<16, false, false><<<dim3(256, 2), 256, 0, stream>>>(
            hin, hmid, e1tF, exp_b1, nullptr, question, cols[r]);
        convm_k<16, false, true><<<dim3(256, 2), 256, 0, stream>>>(
            hmid, hout, e2tF, exp_b2, hin, question, cols[r]);
        float* tp = hin; hin = hout; hout = hmid; hmid = tp;
    }
    // hin == final h (ws+0)

    // head
    projm_k<<<dim3(256, 2), 256, 0, stream>>>(hin, pwF, proj_b, pool3h);
    fc1m_k<<<512, 256, 0, stream>>>(pool3h, fc1_w, fc1p);
    fc1red_k<<<256, 256, 0, stream>>>(fc1p, fc1_b, fc1o);
    fc2a_k<<<dim3(2, 4), 256, 0, stream>>>(fc1o, fc2_w, pfc2);
    fc2b_k<<<1, 512, 0, stream>>>(pfc2, fc2_b, (float*)d_out);
}

// Round 17
// 464.303 us; speedup vs baseline: 1.1596x; 1.0089x over previous
//
#include <hip/hip_runtime.h>
#include <cstddef>

// ---------------------------------------------------------------------------
// SimpleModuleNet. B=256, D=64, E=16, H=W=64, PROJ=512, FC=1024, NA=2.
//
// R2: 64->64 convs on matrix pipe (mfma_f32_16x16x32_f16, f16 hi/lo split).
// R4: proj MFMA + in-lane pool + coalesced writes. R9: pool3 as f16 planes.
// R15: conv1 launch_bounds(256,4) (VGPR budget up -> win[] in regs; worked).
// R16: fc1m dbuf = neutral (82us); kept.
// R17: ALL inter-layer activations stored as f16 hi/lo PLANES (hi [0,NE),
//     lo [NE,2NE); 4 B/elem = footprint-neutral vs fp32). convm staging is
//     now PURE half8 copies (was ~220 convert-VALU/thread/block, barrier-
//     separated from MFMA); projm A-frags and residual reads are pure loads.
//     Epilogues split once at write (identical rounding math -> numerics
//     unchanged). Targets the ~270us aggregate convm fleet (hidden below
//     top-5 cutoff; MFMA floor ~110us).
// ---------------------------------------------------------------------------

typedef _Float16 half8 __attribute__((ext_vector_type(8)));
typedef _Float16 half4_t __attribute__((ext_vector_type(4)));
typedef float f32x4 __attribute__((ext_vector_type(4)));

#define LO_SCALE 2048.0f
#define LO_INV (1.0f / 2048.0f)

// ---------------- generic weight transpose  [o][i](KxK) -> [(i*K+k)][o]
__global__ void transw_k(const float* __restrict__ src, float* __restrict__ dst,
                         int O, int I, int K, int total) {
    int id = blockIdx.x * 256 + threadIdx.x;
    if (id >= total) return;
    int OIK = O * I * K;
    int n = id / OIK, rem = id % OIK;
    int o = rem / (I * K), r2 = rem % (I * K);
    int i = r2 / K, k = r2 % K;
    dst[(size_t)n * OIK + (i * K + k) * O + o] = src[id];
}

// ---------------- conv weight transform: [layer][oc=64][ic=64][3][3] fp32 ->
// f16 fragment layout: idx = (((tap*2+icc)*4+nt)*64 + lane)*8 + j
__global__ void wxform_k(const float* __restrict__ src, _Float16* __restrict__ dst,
                         int nlayers) {
    int id = blockIdx.x * 256 + threadIdx.x;
    if (id >= nlayers * 36864) return;
    int layer = id / 36864, idx = id % 36864;
    int j = idx & 7, l = (idx >> 3) & 63, nt = (idx >> 9) & 3;
    int icc = (idx >> 11) & 1, tap = idx >> 12;
    int kl = (l >> 4) * 8 + j, ic = icc * 32 + kl, oc = nt * 16 + (l & 15);
    float v = src[(size_t)layer * 36864 + (oc * 64 + ic) * 9 + tap];
    _Float16 hi = (_Float16)v;
    _Float16 lo = (_Float16)((v - (float)hi) * LO_SCALE);
    dst[(size_t)layer * 73728 + idx] = hi;
    dst[(size_t)layer * 73728 + 36864 + idx] = lo;
}

// ---------------- proj weight transform: [512 oc][64 ic] fp32 -> B-frag hi/lo
__global__ void pwxform_k(const float* __restrict__ src, _Float16* __restrict__ dst) {
    int id = blockIdx.x * 256 + threadIdx.x;
    if (id >= 32768) return;
    int j = id & 7, l = (id >> 3) & 63, icc = (id >> 9) & 1, nt = id >> 10;
    int kl = (l >> 4) * 8 + j, ic = icc * 32 + kl, oc = nt * 16 + (l & 15);
    float v = src[oc * 64 + ic];
    _Float16 hi = (_Float16)v;
    _Float16 lo = (_Float16)((v - (float)hi) * LO_SCALE);
    dst[id] = hi;
    dst[32768 + id] = lo;
}

// ---------------- conv1: 3->64, 64x64, pad1, +bias, relu, 2x2 maxpool.
// Output: NHWC f16 hi/lo planes, NE1 = 256*32*32*64.
__global__ __launch_bounds__(256, 4)
void conv1_k(const float* __restrict__ img, const float* __restrict__ w0t,
             const float* __restrict__ b0, _Float16* __restrict__ out) {
    const size_t NE1 = 16777216;
    int b = blockIdx.x, tile = blockIdx.y, ocg = blockIdx.z;
    int typ = (tile >> 1) * 16, txp = (tile & 1) * 16;
    int cy0 = typ * 2, cx0 = txp * 2;
    __shared__ float lds[3][34][34];
    const float* imb = img + (size_t)b * 3 * 64 * 64;
    for (int i = threadIdx.x; i < 3 * 34 * 34; i += 256) {
        int c = i / 1156, rem = i % 1156, r = rem / 34, cc = rem % 34;
        int gy = cy0 - 1 + r, gx = cx0 - 1 + cc;
        float v = 0.f;
        if (gy >= 0 && gy < 64 && gx >= 0 && gx < 64) v = imb[(c * 64 + gy) * 64 + gx];
        lds[c][r][cc] = v;
    }
    __syncthreads();
    int pyl = threadIdx.x >> 4, pxl = threadIdx.x & 15;
    float win[3][4][4];
#pragma unroll
    for (int c = 0; c < 3; ++c)
#pragma unroll
        for (int wy = 0; wy < 4; ++wy)
#pragma unroll
            for (int wx = 0; wx < 4; ++wx)
                win[c][wy][wx] = lds[c][2 * pyl + wy][2 * pxl + wx];
    int py = typ + pyl, px = txp + pxl;
    size_t obase = (((size_t)b * 32 + py) * 32 + px) * 64;
#pragma unroll
    for (int q = 0; q < 4; ++q) {
        int ocq = ocg * 4 + q;
        float acc[4][4] = {};
#pragma unroll
        for (int c = 0; c < 3; ++c)
#pragma unroll
            for (int ky = 0; ky < 3; ++ky)
#pragma unroll
                for (int kx = 0; kx < 3; ++kx) {
                    float4 w = *(const float4*)&w0t[(c * 9 + ky * 3 + kx) * 64 + ocq * 4];
                    float wv4[4] = {w.x, w.y, w.z, w.w};
#pragma unroll
                    for (int p2 = 0; p2 < 4; ++p2) {
                        float iv = win[c][(p2 >> 1) + ky][(p2 & 1) + kx];
#pragma unroll
                        for (int o = 0; o < 4; ++o)
                            acc[p2][o] = fmaf(iv, wv4[o], acc[p2][o]);
                    }
                }
        half4_t rh, rl;
#pragma unroll
        for (int o = 0; o < 4; ++o) {
            float bvv = b0[ocq * 4 + o];
            float m = fmaxf(fmaxf(acc[0][o], acc[1][o]), fmaxf(acc[2][o], acc[3][o]));
            float v = fmaxf(m + bvv, 0.f);
            _Float16 h = (_Float16)v;
            rh[o] = h;
            rl[o] = (_Float16)((v - (float)h) * LO_SCALE);
        }
        *(half4_t*)&out[obase + ocq * 4] = rh;
        *(half4_t*)&out[NE1 + obase + ocq * 4] = rl;
    }
}

// ---------------- MFMA conv 64->64 3x3 pad1; in/out/res = f16 hi/lo planes.
// Staging = pure half8 copies (no conversion VALU). Epilogue splits once.
template <int S, bool POOL, bool RES>
__global__ __launch_bounds__(256, 2)
void convm_k(const _Float16* __restrict__ in, _Float16* __restrict__ out,
             const _Float16* __restrict__ wf, const float* __restrict__ bias,
             const _Float16* __restrict__ res, const int* __restrict__ question,
             int qcol) {
    constexpr size_t NEin = (size_t)S * S * 64 * 256;
    constexpr size_t NEout = POOL ? NEin / 4 : NEin;
    int b = blockIdx.x, t = blockIdx.y;
    constexpr int NTX = S / 16;
    int ty0 = (t / NTX) * 8, tx0 = (t % NTX) * 16;

    __shared__ __align__(16) _Float16 lds[2 * 7200];

    int tid = threadIdx.x, lane = tid & 63, wv = tid >> 6;
    const _Float16* wb = wf;
    const float* bb = bias;
    if (question) {
        int idx = question[b * 8 + qcol];
        wb += (size_t)idx * 73728;
        bb += idx * 64;
    }
    float bv[4];
#pragma unroll
    for (int nt = 0; nt < 4; ++nt) bv[nt] = bb[nt * 16 + (lane & 15)];

    f32x4 acc1[2][4] = {};
    f32x4 acc2[2][4] = {};

    int am = lane & 15;
    int k0 = (lane >> 4) * 8;

    for (int icc = 0; icc < 2; ++icc) {
        __syncthreads();
        // stage halo 10x18 x 32ic: pure f16 copies, 720 half8 items
        for (int i = tid; i < 720; i += 256) {
            int pix = i >> 2, j8 = (i & 3) * 8;
            int hy = pix / 18, hx = pix % 18;
            int gy = ty0 + hy - 1, gx = tx0 + hx - 1;
            half8 vh = {}, vl = {};
            if (gy >= 0 && gy < S && gx >= 0 && gx < S) {
                size_t src = (((size_t)b * S + gy) * S + gx) * 64 + icc * 32 + j8;
                vh = *(const half8*)&in[src];
                vl = *(const half8*)&in[NEin + src];
            }
            *(half8*)&lds[pix * 40 + j8] = vh;
            *(half8*)&lds[7200 + pix * 40 + j8] = vl;
        }
        __syncthreads();

#pragma unroll
        for (int ky = 0; ky < 3; ++ky)
#pragma unroll
            for (int kx = 0; kx < 3; ++kx) {
                int tap = ky * 3 + kx;
                const _Float16* wp = wb + (tap * 2 + icc) * 2048 + lane * 8;
                half8 bhi[4], blo[4];
#pragma unroll
                for (int nt = 0; nt < 4; ++nt) {
                    bhi[nt] = *(const half8*)(wp + nt * 512);
                    blo[nt] = *(const half8*)(wp + nt * 512 + 36864);
                }
#pragma unroll
                for (int mt = 0; mt < 2; ++mt) {
                    int MT = wv * 2 + mt;
                    int Q = MT * 4 + (am >> 2), s = am & 3;
                    int py = (Q >> 3) * 2 + (s >> 1), px = (Q & 7) * 2 + (s & 1);
                    const _Float16* ap = &lds[((py + ky) * 18 + (px + kx)) * 40 + k0];
                    half8 ahi = *(const half8*)ap;
                    half8 alo = *(const half8*)(ap + 7200);
#pragma unroll
                    for (int nt = 0; nt < 4; ++nt) {
                        acc1[mt][nt] = __builtin_amdgcn_mfma_f32_16x16x32_f16(
                            ahi, bhi[nt], acc1[mt][nt], 0, 0, 0);
                        acc2[mt][nt] = __builtin_amdgcn_mfma_f32_16x16x32_f16(
                            ahi, blo[nt], acc2[mt][nt], 0, 0, 0);
                        acc2[mt][nt] = __builtin_amdgcn_mfma_f32_16x16x32_f16(
                            alo, bhi[nt], acc2[mt][nt], 0, 0, 0);
                    }
                }
            }
    }

    int cn = lane & 15, rq = lane >> 4;
#pragma unroll
    for (int mt = 0; mt < 2; ++mt) {
        int MT = wv * 2 + mt;
        int Q = MT * 4 + rq;
        int qy = Q >> 3, qx = Q & 7;
#pragma unroll
        for (int nt = 0; nt < 4; ++nt) {
            int oc = nt * 16 + cn;
            float vals[4];
#pragma unroll
            for (int r = 0; r < 4; ++r)
                vals[r] = acc1[mt][nt][r] + acc2[mt][nt][r] * LO_INV + bv[nt];
            if (POOL) {
                float m = fmaxf(fmaxf(vals[0], vals[1]), fmaxf(vals[2], vals[3]));
                m = fmaxf(m, 0.f);
                int opy = (ty0 >> 1) + qy, opx = (tx0 >> 1) + qx;
                size_t o = (((size_t)b * (S / 2) + opy) * (S / 2) + opx) * 64 + oc;
                _Float16 h = (_Float16)m;
                out[o] = h;
                out[NEout + o] = (_Float16)((m - (float)h) * LO_SCALE);
            } else {
#pragma unroll
                for (int r = 0; r < 4; ++r) {
                    int py = qy * 2 + (r >> 1), px = qx * 2 + (r & 1);
                    size_t o = (((size_t)b * S + (ty0 + py)) * S + (tx0 + px)) * 64 + oc;
                    float v = vals[r];
                    if (RES) v += (float)res[o] + (float)res[NEin + o] * LO_INV;
                    v = fmaxf(v, 0.f);
                    _Float16 h = (_Float16)v;
                    out[o] = h;
                    out[NEout + o] = (_Float16)((v - (float)h) * LO_SCALE);
                }
            }
        }
    }
}

// ---------------- proj (MFMA): per-sample GEMM C[256px][512oc], K=64.
// Input h = f16 hi/lo planes (NE2) -> A-frags are pure loads.
// Output: pool3 f16 hi/lo planes (outh, outh+8388608).
__global__ __launch_bounds__(256)
void projm_k(const _Float16* __restrict__ in /* planes, NE2=4194304 */,
             const _Float16* __restrict__ pw, const float* __restrict__ bias,
             _Float16* __restrict__ outh /* hi plane; lo at +8388608 */) {
    const size_t NE2 = 4194304;
    int b = blockIdx.x;
    __shared__ float lt[64 * 65];
    int tid = threadIdx.x, lane = tid & 63, wv = tid >> 6;
    int row = lane & 15, cseg = lane >> 4;

    half8 ah[4][2], al[4][2];
#pragma unroll
    for (int mt = 0; mt < 4; ++mt) {
        int MT = wv * 4 + mt;
        int Q = MT * 4 + (row >> 2), s = row & 3;
        int y = (Q >> 3) * 2 + (s >> 1), x = (Q & 7) * 2 + (s & 1);
        size_t pb = ((size_t)b * 256 + y * 16 + x) * 64 + cseg * 8;
#pragma unroll
        for (int icc = 0; icc < 2; ++icc) {
            ah[mt][icc] = *(const half8*)&in[pb + icc * 32];
            al[mt][icc] = *(const half8*)&in[NE2 + pb + icc * 32];
        }
    }

    for (int ogl = 0; ogl < 4; ++ogl) {
        int og = blockIdx.y * 4 + ogl;
        half8 bh[4][2], bl[4][2];
#pragma unroll
        for (int ntl = 0; ntl < 4; ++ntl)
#pragma unroll
            for (int icc = 0; icc < 2; ++icc) {
                int nt = og * 4 + ntl;
                const _Float16* wp = pw + ((nt * 2 + icc) * 64 + lane) * 8;
                bh[ntl][icc] = *(const half8*)wp;
                bl[ntl][icc] = *(const half8*)(wp + 32768);
            }
        f32x4 a1[4][4] = {};
        f32x4 a2[4][4] = {};
#pragma unroll
        for (int icc = 0; icc < 2; ++icc)
#pragma unroll
            for (int mt = 0; mt < 4; ++mt)
#pragma unroll
                for (int ntl = 0; ntl < 4; ++ntl) {
                    a1[mt][ntl] = __builtin_amdgcn_mfma_f32_16x16x32_f16(
                        ah[mt][icc], bh[ntl][icc], a1[mt][ntl], 0, 0, 0);
                    a2[mt][ntl] = __builtin_amdgcn_mfma_f32_16x16x32_f16(
                        ah[mt][icc], bl[ntl][icc], a2[mt][ntl], 0, 0, 0);
                    a2[mt][ntl] = __builtin_amdgcn_mfma_f32_16x16x32_f16(
                        al[mt][icc], bh[ntl][icc], a2[mt][ntl], 0, 0, 0);
                }
        if (ogl) __syncthreads();
#pragma unroll
        for (int mt = 0; mt < 4; ++mt) {
            int Qg = (wv * 4 + mt) * 4 + (lane >> 4);
#pragma unroll
            for (int ntl = 0; ntl < 4; ++ntl) {
                float bvv = bias[og * 64 + ntl * 16 + (lane & 15)];
                float v0 = a1[mt][ntl][0] + a2[mt][ntl][0] * LO_INV + bvv;
                float v1 = a1[mt][ntl][1] + a2[mt][ntl][1] * LO_INV + bvv;
                float v2 = a1[mt][ntl][2] + a2[mt][ntl][2] * LO_INV + bvv;
                float v3 = a1[mt][ntl][3] + a2[mt][ntl][3] * LO_INV + bvv;
                float m = fmaxf(fmaxf(fmaxf(v0, v1), fmaxf(v2, v3)), 0.f);
                lt[(ntl * 16 + (lane & 15)) * 65 + Qg] = m;
            }
        }
        __syncthreads();
#pragma unroll
        for (int r = 0; r < 16; ++r) {
            int f = r * 256 + tid;
            int ol = f >> 6, q = f & 63;
            float v = lt[ol * 65 + q];
            _Float16 h = (_Float16)v;
            _Float16 l = (_Float16)((v - (float)h) * LO_SCALE);
            size_t o = (size_t)b * 32768 + og * 4096 + ol * 64 + q;
            outh[o] = h;
            outh[8388608 + o] = l;
        }
    }
}

// ---------------- fc1 MFMA GEMM: C[256][1024] = A[256][32768] @ W[1024][32768]^T
// R16 form: double-buffered LDS, one barrier per K-step. A = f16 planes
// (pure-copy staging), W converted in-kernel. Split-K 32, grid 512.
__global__ __launch_bounds__(256)
void fc1m_k(const _Float16* __restrict__ Ahl /* hi; lo at +8388608 */,
            const float* __restrict__ W,
            float* __restrict__ partial /* [32][256][1024] */) {
    int bid = blockIdx.x;
    int lid = (bid & 7) * 64 + (bid >> 3);   // bijective, 512 = 8*64
    int mt = lid & 1, nt = (lid >> 1) & 7, ks = lid >> 4;  // ks 0..31
    int m0 = mt * 128, n0 = nt * 128;
    const _Float16* Ab = Ahl + (size_t)m0 * 32768 + ks * 1024;
    const float* Wb = W + (size_t)n0 * 32768 + ks * 1024;

    __shared__ __align__(16) _Float16 lds[40960];  // 2 buffers x 20480

    int tid = threadIdx.x, lane = tid & 63, wv = tid >> 6;
    int wm = (wv & 1) * 64, wn = (wv >> 1) * 64;
    int koff = (lane >> 4) * 8, fr = lane & 15;

    f32x4 acc1[4][4] = {};
    f32x4 acc2[4][4] = {};

    int arow[2], ak8[2];
#pragma unroll
    for (int p = 0; p < 2; ++p) {
        int idx = p * 256 + tid;
        arow[p] = idx >> 2;
        ak8[p] = (idx & 3) * 8;
    }
    int wrow[4], wc4[4];
#pragma unroll
    for (int p = 0; p < 4; ++p) {
        int idx = p * 256 + tid;
        wrow[p] = idx >> 3;
        wc4[p] = (idx & 7) << 2;
    }

    half8 pa_h[2], pa_l[2];
    float4 rw[4];

#pragma unroll
    for (int p = 0; p < 2; ++p) {
        pa_h[p] = *(const half8*)&Ab[(size_t)arow[p] * 32768 + ak8[p]];
        pa_l[p] = *(const half8*)&Ab[8388608 + (size_t)arow[p] * 32768 + ak8[p]];
    }
#pragma unroll
    for (int p = 0; p < 4; ++p)
        rw[p] = *(const float4*)&Wb[(size_t)wrow[p] * 32768 + wc4[p]];
    {
        _Float16* b0p = lds;
#pragma unroll
        for (int p = 0; p < 2; ++p) {
            *(half8*)&b0p[arow[p] * 40 + ak8[p]] = pa_h[p];
            *(half8*)&b0p[5120 + arow[p] * 40 + ak8[p]] = pa_l[p];
        }
#pragma unroll
        for (int p = 0; p < 4; ++p) {
            float4 u = rw[p];
            _Float16 g0 = (_Float16)u.x, g1 = (_Float16)u.y;
            _Float16 g2 = (_Float16)u.z, g3 = (_Float16)u.w;
            half4_t gh = {g0, g1, g2, g3};
            half4_t gl = {(_Float16)((u.x - (float)g0) * LO_SCALE),
                          (_Float16)((u.y - (float)g1) * LO_SCALE),
                          (_Float16)((u.z - (float)g2) * LO_SCALE),
                          (_Float16)((u.w - (float)g3) * LO_SCALE)};
            *(half4_t*)&b0p[10240 + wrow[p] * 40 + wc4[p]] = gh;
            *(half4_t*)&b0p[15360 + wrow[p] * 40 + wc4[p]] = gl;
        }
    }
#pragma unroll
    for (int p = 0; p < 2; ++p) {
        pa_h[p] = *(const half8*)&Ab[(size_t)arow[p] * 32768 + 32 + ak8[p]];
        pa_l[p] = *(const half8*)&Ab[8388608 + (size_t)arow[p] * 32768 + 32 + ak8[p]];
    }
#pragma unroll
    for (int p = 0; p < 4; ++p)
        rw[p] = *(const float4*)&Wb[(size_t)wrow[p] * 32768 + 32 + wc4[p]];
    __syncthreads();

    for (int kt = 0; kt < 32; ++kt) {
        _Float16* cur = lds + (kt & 1) * 20480;
        _Float16* nxt = lds + ((kt + 1) & 1) * 20480;
        if (kt < 31) {
#pragma unroll
            for (int p = 0; p < 2; ++p) {
                *(half8*)&nxt[arow[p] * 40 + ak8[p]] = pa_h[p];
                *(half8*)&nxt[5120 + arow[p] * 40 + ak8[p]] = pa_l[p];
            }
#pragma unroll
            for (int p = 0; p < 4; ++p) {
                float4 u = rw[p];
                _Float16 g0 = (_Float16)u.x, g1 = (_Float16)u.y;
                _Float16 g2 = (_Float16)u.z, g3 = (_Float16)u.w;
                half4_t gh = {g0, g1, g2, g3};
                half4_t gl = {(_Float16)((u.x - (float)g0) * LO_SCALE),
                              (_Float16)((u.y - (float)g1) * LO_SCALE),
                              (_Float16)((u.z - (float)g2) * LO_SCALE),
                              (_Float16)((u.w - (float)g3) * LO_SCALE)};
                *(half4_t*)&nxt[10240 + wrow[p] * 40 + wc4[p]] = gh;
                *(half4_t*)&nxt[15360 + wrow[p] * 40 + wc4[p]] = gl;
            }
            if (kt < 30) {
                int kb = (kt + 2) * 32;
#pragma unroll
                for (int p = 0; p < 2; ++p) {
                    pa_h[p] = *(const half8*)&Ab[(size_t)arow[p] * 32768 + kb + ak8[p]];
                    pa_l[p] = *(const half8*)&Ab[8388608 + (size_t)arow[p] * 32768 + kb + ak8[p]];
                }
#pragma unroll
                for (int p = 0; p < 4; ++p)
                    rw[p] = *(const float4*)&Wb[(size_t)wrow[p] * 32768 + kb + wc4[p]];
            }
        }
        half8 bh[4], bl[4];
#pragma unroll
        for (int nf = 0; nf < 4; ++nf) {
            int r = wn + nf * 16 + fr;
            bh[nf] = *(const half8*)&cur[10240 + r * 40 + koff];
            bl[nf] = *(const half8*)&cur[15360 + r * 40 + koff];
        }
#pragma unroll
        for (int mf = 0; mf < 4; ++mf) {
            int r = wm + mf * 16 + fr;
            half8 ah = *(const half8*)&cur[r * 40 + koff];
            half8 al = *(const half8*)&cur[5120 + r * 40 + koff];
#pragma unroll
            for (int nf = 0; nf < 4; ++nf) {
                acc1[mf][nf] = __builtin_amdgcn_mfma_f32_16x16x32_f16(
                    ah, bh[nf], acc1[mf][nf], 0, 0, 0);
                acc2[mf][nf] = __builtin_amdgcn_mfma_f32_16x16x32_f16(
                    ah, bl[nf], acc2[mf][nf], 0, 0, 0);
                acc2[mf][nf] = __builtin_amdgcn_mfma_f32_16x16x32_f16(
                    al, bh[nf], acc2[mf][nf], 0, 0, 0);
            }
        }
        __syncthreads();
    }

    int rq = lane >> 4, cn = lane & 15;
    float* pb = partial + (size_t)ks * 262144;
#pragma unroll
    for (int mf = 0; mf < 4; ++mf)
#pragma unroll
        for (int nf = 0; nf < 4; ++nf) {
            int n = n0 + wn + nf * 16 + cn;
#pragma unroll
            for (int r = 0; r < 4; ++r) {
                int m = m0 + wm + mf * 16 + rq * 4 + r;
                pb[(size_t)m * 1024 + n] = acc1[mf][nf][r] + acc2[mf][nf][r] * LO_INV;
            }
        }
}

__global__ __launch_bounds__(256)
void fc1red_k(const float* __restrict__ partial, const float* __restrict__ b1,
              float* __restrict__ fc1o_t /* [n][m] */) {
    int m = blockIdx.x;
    int n0 = threadIdx.x * 4;
    float4 s = {0.f, 0.f, 0.f, 0.f};
    for (int ks = 0; ks < 32; ++ks) {
        float4 v = *(const float4*)&partial[((size_t)ks * 256 + m) * 1024 + n0];
        s.x += v.x; s.y += v.y; s.z += v.z; s.w += v.w;
    }
    fc1o_t[(size_t)(n0 + 0) * 256 + m] = fmaxf(s.x + b1[n0 + 0], 0.f);
    fc1o_t[(size_t)(n0 + 1) * 256 + m] = fmaxf(s.y + b1[n0 + 1], 0.f);
    fc1o_t[(size_t)(n0 + 2) * 256 + m] = fmaxf(s.z + b1[n0 + 2], 0.f);
    fc1o_t[(size_t)(n0 + 3) * 256 + m] = fmaxf(s.w + b1[n0 + 3], 0.f);
}

__global__ __launch_bounds__(256)
void fc2a_k(const float* __restrict__ a_t, const float* __restrict__ W2,
            float* __restrict__ p2) {
    int n2 = blockIdx.x, ks = blockIdx.y;
    int m = threadIdx.x;
    float acc = 0.f;
    for (int k = ks * 256; k < ks * 256 + 256; ++k)
        acc = fmaf(a_t[(size_t)k * 256 + m], W2[n2 * 1024 + k], acc);
    p2[((size_t)n2 * 4 + ks) * 256 + m] = acc;
}

__global__ __launch_bounds__(512)
void fc2b_k(const float* __restrict__ p2, const float* __restrict__ b2,
            float* __restrict__ out) {
    int i = threadIdx.x;
    int m = i >> 1, n2 = i & 1;
    float s = b2[n2];
#pragma unroll
    for (int ks = 0; ks < 4; ++ks) s += p2[((size_t)n2 * 4 + ks) * 256 + m];
    out[m * 2 + n2] = s;
}

// ---------------------------------------------------------------------------
extern "C" void kernel_launch(void* const* d_in, const int* in_sizes, int n_in,
                              void* d_out, int out_size, void* d_ws, size_t ws_size,
                              hipStream_t stream) {
    const float* image   = (const float*)d_in[0];
    const int*   question= (const int*)d_in[1];
    const float* stem_w0 = (const float*)d_in[2];
    const float* stem_b0 = (const float*)d_in[3];
    const float* stem_w  = (const float*)d_in[4];
    const float* stem_b  = (const float*)d_in[5];
    const float* exp_w1  = (const float*)d_in[6];
    const float* exp_b1  = (const float*)d_in[7];
    const float* exp_w2  = (const float*)d_in[8];
    const float* exp_b2  = (const float*)d_in[9];
    const float* proj_w  = (const float*)d_in[10];
    const float* proj_b  = (const float*)d_in[11];
    const float* fc1_w   = (const float*)d_in[12];
    const float* fc1_b   = (const float*)d_in[13];
    const float* fc2_w   = (const float*)d_in[14];
    const float* fc2_b   = (const float*)d_in[15];
    (void)in_sizes; (void)n_in; (void)out_size; (void)ws_size;

    float* ws = (float*)d_ws;
    // Workspace (floats), peak ~156 MB. All activations = f16 hi/lo planes
    // (4 B/elem -> same float-count footprint as before):
    //  [0,A)        p1 planes (NE1=16.8M elems = A floats); later hA/hB/hC
    //               (3*P2N, NE2 planes each); then fc1 partials [32][256][1024]
    //  [A,2A)       h2 planes; later pool3 planes (8.39M elems) + fc1o
    //  [2A,2A+P2N)  p2 planes (NE2=4.2M elems)
    //  [2A+P2N,..)  w0t | proj B-frag f16 | pfc2 | conv f16 weight planes
    const size_t A = 16777216, P2N = 4194304;
    float* wtr   = ws + 2 * A + P2N;
    float* w0t   = wtr;                      // 1728 fp32
    _Float16* pwF = (_Float16*)(wtr + 1728); // 65536 f16
    float* pfc2  = wtr + 1728 + 32768;       // 2048 fp32
    _Float16* f16b = (_Float16*)(wtr + 36544);
    _Float16* stemtF = f16b;                 // 3 layers * 73728 f16
    _Float16* e1tF   = f16b + 3 * 73728;     // 16 layers
    _Float16* e2tF   = e1tF + 16 * 73728;    // 16 layers
    _Float16* p1h  = (_Float16*)ws;
    _Float16* h2h  = (_Float16*)(ws + A);
    _Float16* p2h  = (_Float16*)(ws + 2 * A);
    _Float16* hAh  = (_Float16*)ws;          // p1 dead by then
    _Float16* hBh  = (_Float16*)(ws + P2N);
    _Float16* hCh  = (_Float16*)(ws + 2 * P2N);
    _Float16* pool3h = (_Float16*)(ws + A);  // h2 dead by then
    float* fc1o  = ws + A + 8388608;
    float* fc1p  = ws;                       // [32][256][1024], hA dead after projm

    // weight transforms
    transw_k<<<(1728 + 255) / 256, 256, 0, stream>>>(stem_w0, w0t, 64, 3, 9, 1728);
    pwxform_k<<<128, 256, 0, stream>>>(proj_w, pwF);
    wxform_k<<<(3 * 36864 + 255) / 256, 256, 0, stream>>>(stem_w, stemtF, 3);
    wxform_k<<<(16 * 36864 + 255) / 256, 256, 0, stream>>>(exp_w1, e1tF, 16);
    wxform_k<<<(16 * 36864 + 255) / 256, 256, 0, stream>>>(exp_w2, e2tF, 16);

    // stem
    conv1_k<<<dim3(256, 4, 4), 256, 0, stream>>>(image, w0t, stem_b0, p1h);
    convm_k<32, false, false><<<dim3(256, 8), 256, 0, stream>>>(
        p1h, h2h, stemtF, stem_b, nullptr, nullptr, 0);
    convm_k<32, true, false><<<dim3(256, 8), 256, 0, stream>>>(
        h2h, p2h, stemtF + 73728, stem_b + 64, nullptr, nullptr, 0);
    convm_k<16, false, false><<<dim3(256, 2), 256, 0, stream>>>(
        p2h, hAh, stemtF + 2 * 73728, stem_b + 128, nullptr, nullptr, 0);

    // expert residual rounds (cols 4,5,7)
    const int cols[3] = {4, 5, 7};
    _Float16* hin = hAh;
    _Float16* hmid = hBh;
    _Float16* hout = hCh;
    for (int r = 0; r < 3; ++r) {
        convm_k<16, false, false><<<dim3(256, 2), 256, 0, stream>>>(
            hin, hmid, e1tF, exp_b1, nullptr, question, cols[r]);
        convm_k<16, false, true><<<dim3(256, 2), 256, 0, stream>>>(
            hmid, hout, e2tF, exp_b2, hin, question, cols[r]);
        _Float16* tp = hin; hin = hout; hout = hmid; hmid = tp;
    }
    // hin == final h (ws+0)

    // head
    projm_k<<<dim3(256, 2), 256, 0, stream>>>(hin, pwF, proj_b, pool3h);
    fc1m_k<<<512, 256, 0, stream>>>(pool3h, fc1_w, fc1p);
    fc1red_k<<<256, 256, 0, stream>>>(fc1p, fc1_b, fc1o);
    fc2a_k<<<dim3(2, 4), 256, 0, stream>>>(fc1o, fc2_w, pfc2);
    fc2b_k<<<1, 512, 0, stream>>>(pfc2, fc2_b, (float*)d_out);
}